// Round 19
// baseline (716.344 us; speedup 1.0000x reference)
//
#include <hip/hip_runtime.h>
#include <hip/hip_bf16.h>

typedef __attribute__((ext_vector_type(4))) float f32x4;
typedef __attribute__((ext_vector_type(8))) __bf16 bf16x8;
typedef unsigned short u16;
typedef __attribute__((ext_vector_type(4))) unsigned short u16x4;

__device__ __forceinline__ u16 f2bf(float f) {
  __bf16 h = (__bf16)f;
  return __builtin_bit_cast(u16, h);
}

__device__ __forceinline__ bf16x8 cvt2(f32x4 x, f32x4 y) {
  bf16x8 r;
  r[0] = (__bf16)x[0]; r[1] = (__bf16)x[1]; r[2] = (__bf16)x[2]; r[3] = (__bf16)x[3];
  r[4] = (__bf16)y[0]; r[5] = (__bf16)y[1]; r[6] = (__bf16)y[2]; r[7] = (__bf16)y[3];
  return r;
}

// ---------------- weight fp32 -> bf16 streaming convert (once per call)
__global__ __launch_bounds__(256) void cvt_w(const float* __restrict__ s,
                                             u16* __restrict__ d, int n8) {
  int stride = gridDim.x * 256;
  for (int i = blockIdx.x * 256 + threadIdx.x; i < n8; i += stride) {
    f32x4 a = ((const f32x4*)s)[i * 2];
    f32x4 b = ((const f32x4*)s)[i * 2 + 1];
    *(bf16x8*)(d + (long long)i * 8) = cvt2(a, b);
  }
}

// ---------------- weight GEMM BN=32, fp32 B (round-14/18 verified, fallback)
template<int CMODE, int NBK, int MI>
__global__ __launch_bounds__(512) void gemmW(
    const u16* __restrict__ A, const float* __restrict__ B,
    void* __restrict__ Cv, int K, int ldc)
{
  __shared__ char Bl[2][8192];
  int n0 = blockIdx.x * 32;
  int kb = blockIdx.y * (NBK * 128);
  int m0 = blockIdx.z * (MI * 128);
  int tid = threadIdx.x, lane = tid & 63, w = tid >> 6;
  int r0 = lane & 15, g = lane >> 4;
  int trow = tid >> 4, tcol = tid & 15;

  const float* bsrc = B + (long long)(n0 + trow) * K + kb + tcol * 8;
  const u16* abase = A + (long long)(m0 + w * (MI * 16) + r0) * K + kb + g * 8;
  int swr = (trow & 7) << 4;
  int wofs = trow * 256 + ((tcol * 16) ^ swr);

  {
    f32x4 u = *(const f32x4*)bsrc;
    f32x4 v = *(const f32x4*)(bsrc + 4);
    *(bf16x8*)&Bl[0][wofs] = cvt2(u, v);
  }
  bf16x8 a[2][MI][4];
#pragma unroll
  for (int mi = 0; mi < MI; mi++)
#pragma unroll
    for (int kk = 0; kk < 4; kk++)
      a[0][mi][kk] = *(const bf16x8*)(abase + (long long)mi * 16 * K + kk * 32);

  f32x4 acc[MI][2];
#pragma unroll
  for (int i = 0; i < MI; i++)
#pragma unroll
    for (int j = 0; j < 2; j++) acc[i][j] = (f32x4){0.f, 0.f, 0.f, 0.f};

  __syncthreads();

#pragma unroll
  for (int ibk = 0; ibk < NBK; ibk++) {
    const int cur = ibk & 1;
    const int nxt = cur ^ 1;
    f32x4 u, v;
    if (ibk + 1 < NBK) {
      int ko = (ibk + 1) * 128;
#pragma unroll
      for (int mi = 0; mi < MI; mi++)
#pragma unroll
        for (int kk = 0; kk < 4; kk++)
          a[nxt][mi][kk] = *(const bf16x8*)(abase + (long long)mi * 16 * K + ko + kk * 32);
      u = *(const f32x4*)(bsrc + ko);
      v = *(const f32x4*)(bsrc + ko + 4);
    }
    bf16x8 bfr[2][4];
#pragma unroll
    for (int nj = 0; nj < 2; nj++) {
      int row = nj * 16 + r0;
      int rb = row * 256, sw = (row & 7) << 4;
#pragma unroll
      for (int kk = 0; kk < 4; kk++)
        bfr[nj][kk] = *(const bf16x8*)&Bl[cur][rb + ((kk * 64 + g * 16) ^ sw)];
    }
#pragma unroll
    for (int kk = 0; kk < 4; kk++)
#pragma unroll
      for (int mi = 0; mi < MI; mi++)
#pragma unroll
        for (int nj = 0; nj < 2; nj++)
          acc[mi][nj] = __builtin_amdgcn_mfma_f32_16x16x32_bf16(a[cur][mi][kk], bfr[nj][kk], acc[mi][nj], 0, 0, 0);
    if (ibk + 1 < NBK)
      *(bf16x8*)&Bl[nxt][wofs] = cvt2(u, v);
    __syncthreads();
  }

  long long co = (long long)blockIdx.y * 256 * ldc;
  int rr = (lane >> 4) << 2;
#pragma unroll
  for (int mi = 0; mi < MI; mi++)
#pragma unroll
    for (int nj = 0; nj < 2; nj++)
#pragma unroll
      for (int q = 0; q < 4; q++) {
        int row = m0 + w * (MI * 16) + mi * 16 + rr + q;
        long long idx = co + (long long)row * ldc + n0 + nj * 16 + r0;
        float vv = acc[mi][nj][q];
        if (CMODE == 0) ((float*)Cv)[idx] = vv;
        else            ((u16*)Cv)[idx] = f2bf(vv);
      }
}

// ---------------- weight GEMM BN=32, bf16 B, BK=256 slabs (two A-halves).
// grid (N/32, ksplit, msplit). NSL = slabs of 256 k per block. Wave = 16 rows.
// B tile 32 rows x 256 k bf16 = 16KB/slab, dbuf. Stage: 512 thr x 32B.
template<int CMODE, int NSL>
__global__ __launch_bounds__(512) void gemmWB(
    const u16* __restrict__ A, const u16* __restrict__ Bw,
    void* __restrict__ Cv, int K, int ldc)
{
  __shared__ char Bl[2][16384];
  int n0 = blockIdx.x * 32;
  int kb = blockIdx.y * (NSL * 256);
  int m0 = blockIdx.z * 128;
  int tid = threadIdx.x, lane = tid & 63, w = tid >> 6;
  int r0 = lane & 15, g = lane >> 4;
  int trow = tid >> 4, tc = tid & 15;

  const u16* bsrc = Bw + (long long)(n0 + trow) * K + kb + tc * 16;
  const u16* abase = A + (long long)(m0 + w * 16 + r0) * K + kb + g * 8;
  int swr = (trow & 7) << 4;
  int sofsA = trow * 512 + ((tc * 32) ^ swr);
  int sofsB = trow * 512 + ((tc * 32 + 16) ^ swr);

  *(bf16x8*)&Bl[0][sofsA] = *(const bf16x8*)bsrc;
  *(bf16x8*)&Bl[0][sofsB] = *(const bf16x8*)(bsrc + 8);

  bf16x8 aH0[4];
#pragma unroll
  for (int kk = 0; kk < 4; kk++)
    aH0[kk] = *(const bf16x8*)(abase + kk * 32);

  f32x4 acc[2];
  acc[0] = (f32x4){0.f, 0.f, 0.f, 0.f};
  acc[1] = (f32x4){0.f, 0.f, 0.f, 0.f};

  __syncthreads();

#pragma unroll
  for (int s = 0; s < NSL; s++) {
    const int cur = s & 1;
    const int nxt = cur ^ 1;
    bf16x8 aH1[4], aN0[4], bp0, bp1;
#pragma unroll
    for (int kk = 0; kk < 4; kk++)
      aH1[kk] = *(const bf16x8*)(abase + s * 256 + 128 + kk * 32);
    if (s + 1 < NSL) {
      int ko = (s + 1) * 256;
      bp0 = *(const bf16x8*)(bsrc + ko);
      bp1 = *(const bf16x8*)(bsrc + ko + 8);
#pragma unroll
      for (int kk = 0; kk < 4; kk++)
        aN0[kk] = *(const bf16x8*)(abase + ko + kk * 32);
    }
#pragma unroll
    for (int h = 0; h < 2; h++) {
#pragma unroll
      for (int kk = 0; kk < 4; kk++) {
        bf16x8 af = h == 0 ? aH0[kk] : aH1[kk];
#pragma unroll
        for (int nj = 0; nj < 2; nj++) {
          int row = nj * 16 + r0;
          int j = h * 16 + kk * 4 + g;
          bf16x8 bf = *(const bf16x8*)&Bl[cur][row * 512 + ((j * 16) ^ ((row & 7) << 4))];
          acc[nj] = __builtin_amdgcn_mfma_f32_16x16x32_bf16(af, bf, acc[nj], 0, 0, 0);
        }
      }
    }
    if (s + 1 < NSL) {
      *(bf16x8*)&Bl[nxt][sofsA] = bp0;
      *(bf16x8*)&Bl[nxt][sofsB] = bp1;
#pragma unroll
      for (int kk = 0; kk < 4; kk++) aH0[kk] = aN0[kk];
    }
    __syncthreads();
  }

  long long co = (long long)blockIdx.y * 256 * ldc;
  int rr = (lane >> 4) << 2;
#pragma unroll
  for (int nj = 0; nj < 2; nj++)
#pragma unroll
    for (int q = 0; q < 4; q++) {
      int row = m0 + w * 16 + rr + q;
      long long idx = co + (long long)row * ldc + n0 + nj * 16 + r0;
      float vv = acc[nj][q];
      if (CMODE == 0) ((float*)Cv)[idx] = vv;
      else            ((u16*)Cv)[idx] = f2bf(vv);
    }
}

// ---------------- gate_up GEMM, bf16 B, BK=256 + fused silu. grid (256, 2).
// B tile rows 0..15 = gate rows n0+trow, 16..31 = up rows 4096+n0+trow-16.
__global__ __launch_bounds__(512) void gemmGUB(
    const u16* __restrict__ A, const u16* __restrict__ Bw,
    u16* __restrict__ y)
{
  const int K = 1024, NSL = 4;
  __shared__ char Bl[2][16384];
  int n0 = blockIdx.x * 16;
  int m0 = blockIdx.y * 128;
  int tid = threadIdx.x, lane = tid & 63, w = tid >> 6;
  int r0 = lane & 15, g = lane >> 4;
  int trow = tid >> 4, tc = tid & 15;

  const u16* brow = (trow < 16)
      ? (Bw + (long long)(n0 + trow) * K)
      : (Bw + (long long)(4096 + n0 + trow - 16) * K);
  const u16* bsrc = brow + tc * 16;
  const u16* abase = A + (long long)(m0 + w * 16 + r0) * K + g * 8;
  int swr = (trow & 7) << 4;
  int sofsA = trow * 512 + ((tc * 32) ^ swr);
  int sofsB = trow * 512 + ((tc * 32 + 16) ^ swr);

  *(bf16x8*)&Bl[0][sofsA] = *(const bf16x8*)bsrc;
  *(bf16x8*)&Bl[0][sofsB] = *(const bf16x8*)(bsrc + 8);

  bf16x8 aH0[4];
#pragma unroll
  for (int kk = 0; kk < 4; kk++)
    aH0[kk] = *(const bf16x8*)(abase + kk * 32);

  f32x4 acc[2];
  acc[0] = (f32x4){0.f, 0.f, 0.f, 0.f};
  acc[1] = (f32x4){0.f, 0.f, 0.f, 0.f};

  __syncthreads();

#pragma unroll
  for (int s = 0; s < NSL; s++) {
    const int cur = s & 1;
    const int nxt = cur ^ 1;
    bf16x8 aH1[4], aN0[4], bp0, bp1;
#pragma unroll
    for (int kk = 0; kk < 4; kk++)
      aH1[kk] = *(const bf16x8*)(abase + s * 256 + 128 + kk * 32);
    if (s + 1 < NSL) {
      int ko = (s + 1) * 256;
      bp0 = *(const bf16x8*)(bsrc + ko);
      bp1 = *(const bf16x8*)(bsrc + ko + 8);
#pragma unroll
      for (int kk = 0; kk < 4; kk++)
        aN0[kk] = *(const bf16x8*)(abase + ko + kk * 32);
    }
#pragma unroll
    for (int h = 0; h < 2; h++) {
#pragma unroll
      for (int kk = 0; kk < 4; kk++) {
        bf16x8 af = h == 0 ? aH0[kk] : aH1[kk];
#pragma unroll
        for (int nj = 0; nj < 2; nj++) {
          int row = nj * 16 + r0;
          int j = h * 16 + kk * 4 + g;
          bf16x8 bf = *(const bf16x8*)&Bl[cur][row * 512 + ((j * 16) ^ ((row & 7) << 4))];
          acc[nj] = __builtin_amdgcn_mfma_f32_16x16x32_bf16(af, bf, acc[nj], 0, 0, 0);
        }
      }
    }
    if (s + 1 < NSL) {
      *(bf16x8*)&Bl[nxt][sofsA] = bp0;
      *(bf16x8*)&Bl[nxt][sofsB] = bp1;
#pragma unroll
      for (int kk = 0; kk < 4; kk++) aH0[kk] = aN0[kk];
    }
    __syncthreads();
  }

  int rr = (lane >> 4) << 2;
#pragma unroll
  for (int q = 0; q < 4; q++) {
    int row = m0 + w * 16 + rr + q;
    float gv = acc[0][q], uv = acc[1][q];
    y[(long long)row * 4096 + n0 + r0] = f2bf((gv / (1.0f + __expf(-gv))) * uv);
  }
}

// ---------------- gate_up GEMM + fused silu, fp32 B (round-18 fallback)
__global__ __launch_bounds__(512) void gemmGU(
    const u16* __restrict__ A, const float* __restrict__ B,
    u16* __restrict__ y)
{
  const int K = 1024, NBK = 8;
  __shared__ char Bl[2][8192];
  int n0 = blockIdx.x * 16;
  int m0 = blockIdx.y * 128;
  int tid = threadIdx.x, lane = tid & 63, w = tid >> 6;
  int r0 = lane & 15, g = lane >> 4;
  int trow = tid >> 4, tcol = tid & 15;

  const float* brow = (trow < 16)
      ? (B + (long long)(n0 + trow) * K)
      : (B + (long long)(4096 + n0 + trow - 16) * K);
  const float* bsrc = brow + tcol * 8;
  const u16* abase = A + (long long)(m0 + w * 16 + r0) * K + g * 8;
  int swr = (trow & 7) << 4;
  int wofs = trow * 256 + ((tcol * 16) ^ swr);

  {
    f32x4 u = *(const f32x4*)bsrc;
    f32x4 v = *(const f32x4*)(bsrc + 4);
    *(bf16x8*)&Bl[0][wofs] = cvt2(u, v);
  }
  bf16x8 a[2][4];
#pragma unroll
  for (int kk = 0; kk < 4; kk++)
    a[0][kk] = *(const bf16x8*)(abase + kk * 32);

  f32x4 acc[2];
  acc[0] = (f32x4){0.f, 0.f, 0.f, 0.f};
  acc[1] = (f32x4){0.f, 0.f, 0.f, 0.f};

  __syncthreads();

#pragma unroll
  for (int ibk = 0; ibk < NBK; ibk++) {
    const int cur = ibk & 1;
    const int nxt = cur ^ 1;
    f32x4 u, v;
    if (ibk + 1 < NBK) {
      int ko = (ibk + 1) * 128;
#pragma unroll
      for (int kk = 0; kk < 4; kk++)
        a[nxt][kk] = *(const bf16x8*)(abase + ko + kk * 32);
      u = *(const f32x4*)(bsrc + ko);
      v = *(const f32x4*)(bsrc + ko + 4);
    }
    bf16x8 bfr[2][4];
#pragma unroll
    for (int nj = 0; nj < 2; nj++) {
      int row = nj * 16 + r0;
      int rb = row * 256, sw = (row & 7) << 4;
#pragma unroll
      for (int kk = 0; kk < 4; kk++)
        bfr[nj][kk] = *(const bf16x8*)&Bl[cur][rb + ((kk * 64 + g * 16) ^ sw)];
    }
#pragma unroll
    for (int kk = 0; kk < 4; kk++)
#pragma unroll
      for (int nj = 0; nj < 2; nj++)
        acc[nj] = __builtin_amdgcn_mfma_f32_16x16x32_bf16(a[cur][kk], bfr[nj][kk], acc[nj], 0, 0, 0);
    if (ibk + 1 < NBK)
      *(bf16x8*)&Bl[nxt][wofs] = cvt2(u, v);
    __syncthreads();
  }

  int rr = (lane >> 4) << 2;
#pragma unroll
  for (int q = 0; q < 4; q++) {
    int row = m0 + w * 16 + rr + q;
    float gv = acc[0][q], uv = acc[1][q];
    y[(long long)row * 4096 + n0 + r0] = f2bf((gv / (1.0f + __expf(-gv))) * uv);
  }
}

// ---------------- fused residual + rmsnorm (sum variant)
__global__ __launch_bounds__(256) void rms_fuse(const float* __restrict__ src,
                                                const float* __restrict__ parts, int np,
                                                float* __restrict__ hout, u16* __restrict__ x) {
  int s = blockIdx.x, tid = threadIdx.x;
  __shared__ float red[4];
  f32x4 hv = ((const f32x4*)(src + s * 1024))[tid];
  for (int p = 0; p < np; p++) {
    f32x4 pv = ((const f32x4*)(parts + (long long)p * 262144 + s * 1024))[tid];
    hv[0] += pv[0]; hv[1] += pv[1]; hv[2] += pv[2]; hv[3] += pv[3];
  }
  float ss = hv[0]*hv[0] + hv[1]*hv[1] + hv[2]*hv[2] + hv[3]*hv[3];
#pragma unroll
  for (int off = 32; off > 0; off >>= 1) ss += __shfl_xor(ss, off, 64);
  int lane = tid & 63, w = tid >> 6;
  if (lane == 0) red[w] = ss;
  __syncthreads();
  ss = red[0] + red[1] + red[2] + red[3];
  float r = 1.0f / sqrtf(ss);
  ((f32x4*)(hout + s * 1024))[tid] = hv;
  u16x4 o;
#pragma unroll
  for (int c = 0; c < 4; c++) o[c] = f2bf(hv[c] * r);
  ((u16x4*)x)[s * 256 + tid] = o;
}

// ---------------- final norm
__global__ __launch_bounds__(256) void final_fuse(const float* __restrict__ src,
                                                  const float* __restrict__ parts, int np,
                                                  const float* __restrict__ nw,
                                                  float* __restrict__ out) {
  int s = blockIdx.x, tid = threadIdx.x;
  __shared__ float red[4];
  f32x4 hv = ((const f32x4*)(src + s * 1024))[tid];
  for (int p = 0; p < np; p++) {
    f32x4 pv = ((const f32x4*)(parts + (long long)p * 262144 + s * 1024))[tid];
    hv[0] += pv[0]; hv[1] += pv[1]; hv[2] += pv[2]; hv[3] += pv[3];
  }
  float ss = hv[0]*hv[0] + hv[1]*hv[1] + hv[2]*hv[2] + hv[3]*hv[3];
#pragma unroll
  for (int off = 32; off > 0; off >>= 1) ss += __shfl_xor(ss, off, 64);
  int lane = tid & 63, w = tid >> 6;
  if (lane == 0) red[w] = ss;
  __syncthreads();
  ss = red[0] + red[1] + red[2] + red[3];
  float r = 1.0f / sqrtf(ss * (1.0f / 1024.0f) + 1e-6f);
  f32x4 wv = ((const f32x4*)nw)[tid];
  f32x4 o; o[0]=hv[0]*r*wv[0]; o[1]=hv[1]*r*wv[1]; o[2]=hv[2]*r*wv[2]; o[3]=hv[3]*r*wv[3];
  ((f32x4*)(out + s * 1024))[tid] = o;
}

// ---------------- transpose ALL layers' past K/V (once)
__global__ __launch_bounds__(256) void transpose_past(const float* __restrict__ pk,
                                                      const float* __restrict__ pv,
                                                      u16* __restrict__ Kb, u16* __restrict__ Vb) {
  __shared__ float tile[64][65];
  int t0 = blockIdx.x * 64;
  int kvh = blockIdx.y;
  int l = blockIdx.z >> 1, part = blockIdx.z & 1;
  int lk = l * 2 + kvh;
  int tid = threadIdx.x;
  if (part == 0) {
    const float* src = pk + (long long)lk * 64 * 2048;        // [d][t]
#pragma unroll
    for (int r = 0; r < 16; r++) {
      int idx = r * 256 + tid; int d = idx >> 6, t = idx & 63;
      tile[d][t] = src[d * 2048 + t0 + t];
    }
    __syncthreads();
    u16* dst = Kb + (long long)lk * 2304 * 64;                // [t][d]
#pragma unroll
    for (int r = 0; r < 16; r++) {
      int idx = r * 256 + tid; int t = idx >> 6, d = idx & 63;
      dst[(t0 + t) * 64 + d] = f2bf(tile[d][t]);
    }
  } else {
    const float* src = pv + (long long)lk * 2048 * 64;        // [t][d]
#pragma unroll
    for (int r = 0; r < 16; r++) {
      int idx = r * 256 + tid; int t = idx >> 6, d = idx & 63;
      tile[t][d] = src[(t0 + t) * 64 + d];
    }
    __syncthreads();
    u16* dst = Vb + (long long)lk * 64 * 2304;                // [d][t]
#pragma unroll
    for (int r = 0; r < 16; r++) {
      int idx = r * 256 + tid; int d = idx >> 6, t = idx & 63;
      dst[d * 2304 + t0 + t] = f2bf(tile[t][d]);
    }
  }
}

// ---------------- rope (sums 4 qkv partials) + scatter new q/k/v
__global__ __launch_bounds__(256) void rope_qkv(const float* __restrict__ P,
                                                const float* __restrict__ cs,
                                                const float* __restrict__ sn,
                                                u16* __restrict__ qb,
                                                u16* __restrict__ Kb,
                                                u16* __restrict__ Vb) {
  int s = blockIdx.x, tid = threadIdx.x;
  long long o0 = (long long)s * 1280;
  for (int i = tid; i < 1280; i += 256) {
    int hh = i >> 6, d = i & 63;
    float v = P[o0 + i] + P[327680 + o0 + i] + P[655360 + o0 + i] + P[983040 + o0 + i];
    if (hh < 18) {
      int j = (hh << 6) | ((d + 32) & 63);
      float vr = P[o0 + j] + P[327680 + o0 + j] + P[655360 + o0 + j] + P[983040 + o0 + j];
      v = v * cs[s * 64 + d] + vr * sn[s * 64 + d];
      if (hh < 16) qb[hh * 16384 + s * 64 + d] = f2bf(v);
      else         Kb[(hh - 16) * 147456 + (2048 + s) * 64 + d] = f2bf(v);
    } else {
      Vb[(hh - 18) * 147456 + d * 2304 + 2048 + s] = f2bf(v);
    }
  }
}

// ---------------- flash attention, 8-wave (verified round-14)
struct KV { bf16x8 kf[2][2]; bf16x8 vf[4]; };

__global__ __launch_bounds__(512) void flash_attn(
    const u16* __restrict__ qb, const u16* __restrict__ Kb2,
    const u16* __restrict__ Vb2, u16* __restrict__ oacc)
{
  __shared__ u16 Plds[8][16][36];
  __shared__ float Osh[8][16][68];
  __shared__ float msh[8][16];
  __shared__ float lsh[8][16];

  int hh = blockIdx.y, kvh = hh >> 3;
  int s0 = blockIdx.x * 16;
  int tid = threadIdx.x, lane = tid & 63, w = tid >> 6;
  int g = lane >> 4, r0 = lane & 15;

  const u16* Q  = qb  + hh * (256 * 64);
  const u16* Kh = Kb2 + kvh * (2304 * 64);
  const u16* Vh = Vb2 + kvh * (64 * 2304);

  bf16x8 qf[2];
#pragma unroll
  for (int kk = 0; kk < 2; kk++)
    qf[kk] = *(const bf16x8*)(Q + (s0 + r0) * 64 + kk * 32 + g * 8);

  f32x4 O[4];
#pragma unroll
  for (int dj = 0; dj < 4; dj++) O[dj] = (f32x4){0.f, 0.f, 0.f, 0.f};
  float m = -1e30f, l = 0.f;

  int t0s = w * 288;

  auto loadkv = [&](KV& d, int t0) {
#pragma unroll
    for (int tj = 0; tj < 2; tj++)
#pragma unroll
      for (int kk = 0; kk < 2; kk++)
        d.kf[tj][kk] = *(const bf16x8*)(Kh + (t0 + tj * 16 + r0) * 64 + kk * 32 + g * 8);
#pragma unroll
    for (int dj = 0; dj < 4; dj++)
      d.vf[dj] = *(const bf16x8*)(Vh + (dj * 16 + r0) * 2304 + t0 + g * 8);
  };

  auto step = [&](KV& kv, int t0) {
    f32x4 sc[2];
#pragma unroll
    for (int tj = 0; tj < 2; tj++) {
      f32x4 z = (f32x4){0.f, 0.f, 0.f, 0.f};
      z = __builtin_amdgcn_mfma_f32_16x16x32_bf16(kv.kf[tj][0], qf[0], z, 0, 0, 0);
      z = __builtin_amdgcn_mfma_f32_16x16x32_bf16(kv.kf[tj][1], qf[1], z, 0, 0, 0);
      sc[tj] = z;
    }
    if (t0 + 31 > 2048 + s0) {
#pragma unroll
      for (int tj = 0; tj < 2; tj++)
#pragma unroll
        for (int q = 0; q < 4; q++) {
          int tg = t0 + tj * 16 + g * 4 + q;
          int sg = s0 + r0;
          if (tg > 2048 + sg) sc[tj][q] = -1e30f;
        }
    }
    float rm = -1e30f;
#pragma unroll
    for (int tj = 0; tj < 2; tj++)
#pragma unroll
      for (int q = 0; q < 4; q++) rm = fmaxf(rm, sc[tj][q]);
    rm = fmaxf(rm, __shfl_xor(rm, 16, 64));
    rm = fmaxf(rm, __shfl_xor(rm, 32, 64));
    float mn = fmaxf(m, rm);
    float sca = __expf(m - mn);
    float rs = 0.f;
#pragma unroll
    for (int tj = 0; tj < 2; tj++)
#pragma unroll
      for (int q = 0; q < 4; q++) {
        sc[tj][q] = __expf(sc[tj][q] - mn);
        rs += sc[tj][q];
      }
    rs += __shfl_xor(rs, 16, 64);
    rs += __shfl_xor(rs, 32, 64);
    l = l * sca + rs;
    m = mn;
#pragma unroll
    for (int dj = 0; dj < 4; dj++) {
      O[dj][0] *= sca; O[dj][1] *= sca; O[dj][2] *= sca; O[dj][3] *= sca;
    }
#pragma unroll
    for (int tj = 0; tj < 2; tj++) {
      u16x4 pw;
#pragma unroll
      for (int q = 0; q < 4; q++) pw[q] = f2bf(sc[tj][q]);
      *(u16x4*)&Plds[w][r0][tj * 16 + g * 4] = pw;
    }
    u16x4 plo = *(const u16x4*)&Plds[w][r0][g * 8];
    u16x4 phi = *(const u16x4*)&Plds[w][r0][g * 8 + 4];
    union { bf16x8 v; u16x4 h[2]; } pu;
    pu.h[0] = plo; pu.h[1] = phi;
#pragma unroll
    for (int dj = 0; dj < 4; dj++)
      O[dj] = __builtin_amdgcn_mfma_f32_16x16x32_bf16(kv.vf[dj], pu.v, O[dj], 0, 0, 0);
  };

  KV ba, bb;
  loadkv(ba, t0s);
#pragma unroll 1
  for (int p = 0; p < 4; p++) {
    int t0 = t0s + p * 64;
    loadkv(bb, t0 + 32);
    step(ba, t0);
    loadkv(ba, t0 + 64);
    step(bb, t0 + 32);
  }
  step(ba, t0s + 256);

#pragma unroll
  for (int dj = 0; dj < 4; dj++)
    *(f32x4*)&Osh[w][r0][dj * 16 + g * 4] = O[dj];
  if (g == 0) { msh[w][r0] = m; lsh[w][r0] = l; }
  __syncthreads();

  if (tid < 256) {
    int row = tid >> 4, c0 = (tid & 15) * 4;
    float M = -1e30f;
#pragma unroll
    for (int w8 = 0; w8 < 8; w8++) M = fmaxf(M, msh[w8][row]);
    float L = 0.f;
    float a0 = 0.f, a1 = 0.f, a2 = 0.f, a3 = 0.f;
#pragma unroll
    for (int w8 = 0; w8 < 8; w8++) {
      float e = __expf(msh[w8][row] - M);
      L += lsh[w8][row] * e;
      f32x4 ov = *(const f32x4*)&Osh[w8][row][c0];
      a0 += e * ov[0]; a1 += e * ov[1]; a2 += e * ov[2]; a3 += e * ov[3];
    }
    float inv = 1.0f / L;
    u16x4 o4;
    o4[0] = f2bf(a0 * inv); o4[1] = f2bf(a1 * inv);
    o4[2] = f2bf(a2 * inv); o4[3] = f2bf(a3 * inv);
    *(u16x4*)(oacc + (long long)(s0 + row) * 1024 + hh * 64 + c0) = o4;
  }
}

// ---------------- launch ----------------
extern "C" void kernel_launch(void* const* d_in, const int* in_sizes, int n_in,
                              void* d_out, int out_size, void* d_ws, size_t ws_size,
                              hipStream_t stream) {
  (void)in_sizes; (void)n_in; (void)out_size;
  const float* hs   = (const float*)d_in[0];
  const float* rc   = (const float*)d_in[1];
  const float* rs   = (const float*)d_in[2];
  const float* pk   = (const float*)d_in[4];
  const float* pv   = (const float*)d_in[5];
  const float* qkvw = (const float*)d_in[6];
  const float* ow   = (const float*)d_in[7];
  const float* guw  = (const float*)d_in[8];
  const float* dw   = (const float*)d_in[9];
  const float* nw   = (const float*)d_in[10];
  float* out = (float*)d_out;

  char* base = (char*)d_ws;
  float* h   = (float*)(base + 0);            // 1 MB
  u16*  x    = (u16*)(base + 1048576);        // 0.5 MB
  float* Pq  = (float*)(base + 1572864);      // 5 MB    [4][256][1280]
  float* Po  = (float*)(base + 6815744);      // 4 MB    [4][256][1024]
  float* Pd  = (float*)(base + 11010048);     // 4 MB    [4][256][1024]
  u16*  y    = (u16*)(base + 15204352);       // 2 MB    [256][4096] bf16
  u16*  oacc = (u16*)(base + 17301504);       // 0.5 MB
  u16*  qb   = (u16*)(base + 17825792);       // 0.5 MB
  u16*  Kb   = (u16*)(base + 18350080);       // 4.5 MB  [8][2][2304][64]
  u16*  Vb   = (u16*)(base + 23068672);       // 4.5 MB  [8][2][64][2304]
  // bf16 weight mirrors (only used when ws_size permits)
  u16*  qkvwB = (u16*)(base + 33554432);      // 20 MB
  u16*  owB   = (u16*)(base + 54525952);      // 16 MB
  u16*  guwB  = (u16*)(base + 71303168);      // 128 MB
  u16*  dwB   = (u16*)(base + 205520896);     // 64 MB
  const bool BF16W = ws_size >= 272629760ULL; // 260 MB

  if (BF16W) {
    cvt_w<<<2048, 256, 0, stream>>>(qkvw, qkvwB, 1310720);
    cvt_w<<<2048, 256, 0, stream>>>(ow, owB, 1048576);
    cvt_w<<<8192, 256, 0, stream>>>(guw, guwB, 8388608);
    cvt_w<<<4096, 256, 0, stream>>>(dw, dwB, 4194304);
  }
  transpose_past<<<dim3(32, 2, 16), 256, 0, stream>>>(pk, pv, Kb, Vb);

  for (int l = 0; l < 8; ++l) {
    u16* Kbl = Kb + (long long)l * 2 * 2304 * 64;
    u16* Vbl = Vb + (long long)l * 2 * 64 * 2304;

    if (l == 0)
      rms_fuse<<<256, 256, 0, stream>>>(hs, nullptr, 0, h, x);
    else
      rms_fuse<<<256, 256, 0, stream>>>(h, Pd, 4, h, x);

    if (BF16W) {
      gemmWB<0, 1><<<dim3(40, 4, 2), 512, 0, stream>>>(
          x, qkvwB + (long long)l * 1310720, Pq, 1024, 1280);
    } else {
      gemmW<0, 2, 1><<<dim3(40, 4, 2), 512, 0, stream>>>(
          x, qkvw + (long long)l * 1310720, Pq, 1024, 1280);
    }
    rope_qkv<<<256, 256, 0, stream>>>(Pq, rc, rs, qb, Kbl, Vbl);
    flash_attn<<<dim3(16, 16), 512, 0, stream>>>(qb, Kbl, Vbl, oacc);
    if (BF16W) {
      gemmWB<0, 1><<<dim3(32, 4, 2), 512, 0, stream>>>(
          oacc, owB + (long long)l * 1048576, Po, 1024, 1024);
    } else {
      gemmW<0, 2, 1><<<dim3(32, 4, 2), 512, 0, stream>>>(
          oacc, ow + (long long)l * 1048576, Po, 1024, 1024);
    }
    rms_fuse<<<256, 256, 0, stream>>>(h, Po, 4, h, x);
    if (BF16W) {
      gemmGUB<<<dim3(256, 2), 512, 0, stream>>>(
          x, guwB + (long long)l * 8388608, y);
      gemmWB<0, 4><<<dim3(32, 4, 2), 512, 0, stream>>>(
          y, dwB + (long long)l * 4194304, Pd, 4096, 1024);
    } else {
      gemmGU<<<dim3(256, 2), 512, 0, stream>>>(
          x, guw + (long long)l * 8388608, y);
      gemmW<0, 8, 1><<<dim3(32, 4, 2), 512, 0, stream>>>(
          y, dw + (long long)l * 4194304, Pd, 4096, 1024);
    }
  }
  final_fuse<<<256, 256, 0, stream>>>(h, Pd, 4, nw, out);
}

// Round 20
// 628.627 us; speedup vs baseline: 1.1395x; 1.1395x over previous
//
#include <hip/hip_runtime.h>
#include <hip/hip_bf16.h>

typedef __attribute__((ext_vector_type(4))) float f32x4;
typedef __attribute__((ext_vector_type(8))) __bf16 bf16x8;
typedef unsigned short u16;
typedef __attribute__((ext_vector_type(4))) unsigned short u16x4;

__device__ __forceinline__ u16 f2bf(float f) {
  __bf16 h = (__bf16)f;
  return __builtin_bit_cast(u16, h);
}

__device__ __forceinline__ bf16x8 cvt2(f32x4 x, f32x4 y) {
  bf16x8 r;
  r[0] = (__bf16)x[0]; r[1] = (__bf16)x[1]; r[2] = (__bf16)x[2]; r[3] = (__bf16)x[3];
  r[4] = (__bf16)y[0]; r[5] = (__bf16)y[1]; r[6] = (__bf16)y[2]; r[7] = (__bf16)y[3];
  return r;
}

// ---------------- weight GEMM BN=32 (round-13/14 verified kernel + guarded
// 2-slab-ahead B prefetch; NBK<=2 behavior identical to verified version.)
template<int CMODE, int NBK, int MI>
__global__ __launch_bounds__(512) void gemmW(
    const u16* __restrict__ A, const float* __restrict__ B,
    void* __restrict__ Cv, int K, int ldc)
{
  __shared__ char Bl[2][8192];
  int n0 = blockIdx.x * 32;
  int kb = blockIdx.y * (NBK * 128);
  int m0 = blockIdx.z * (MI * 128);
  int tid = threadIdx.x, lane = tid & 63, w = tid >> 6;
  int r0 = lane & 15, g = lane >> 4;
  int trow = tid >> 4, tcol = tid & 15;

  const float* bsrc = B + (long long)(n0 + trow) * K + kb + tcol * 8;
  const u16* abase = A + (long long)(m0 + w * (MI * 16) + r0) * K + kb + g * 8;
  int swr = (trow & 7) << 4;
  int wofs = trow * 256 + ((tcol * 16) ^ swr);

  {
    f32x4 u = *(const f32x4*)bsrc;
    f32x4 v = *(const f32x4*)(bsrc + 4);
    *(bf16x8*)&Bl[0][wofs] = cvt2(u, v);
  }
  f32x4 bu[2][2];
  if (NBK > 1) {
    bu[1][0] = *(const f32x4*)(bsrc + 128);
    bu[1][1] = *(const f32x4*)(bsrc + 132);
  }
  bf16x8 a[2][MI][4];
#pragma unroll
  for (int mi = 0; mi < MI; mi++)
#pragma unroll
    for (int kk = 0; kk < 4; kk++)
      a[0][mi][kk] = *(const bf16x8*)(abase + (long long)mi * 16 * K + kk * 32);

  f32x4 acc[MI][2];
#pragma unroll
  for (int i = 0; i < MI; i++)
#pragma unroll
    for (int j = 0; j < 2; j++) acc[i][j] = (f32x4){0.f, 0.f, 0.f, 0.f};

  __syncthreads();

#pragma unroll
  for (int ibk = 0; ibk < NBK; ibk++) {
    const int cur = ibk & 1;
    const int nxt = cur ^ 1;
    if (ibk + 2 < NBK) {
      int ko2 = (ibk + 2) * 128;
      bu[ibk & 1][0] = *(const f32x4*)(bsrc + ko2);
      bu[ibk & 1][1] = *(const f32x4*)(bsrc + ko2 + 4);
    }
    if (ibk + 1 < NBK) {
      int ko = (ibk + 1) * 128;
#pragma unroll
      for (int mi = 0; mi < MI; mi++)
#pragma unroll
        for (int kk = 0; kk < 4; kk++)
          a[nxt][mi][kk] = *(const bf16x8*)(abase + (long long)mi * 16 * K + ko + kk * 32);
    }
    bf16x8 bfr[2][4];
#pragma unroll
    for (int nj = 0; nj < 2; nj++) {
      int row = nj * 16 + r0;
      int rb = row * 256, sw = (row & 7) << 4;
#pragma unroll
      for (int kk = 0; kk < 4; kk++)
        bfr[nj][kk] = *(const bf16x8*)&Bl[cur][rb + ((kk * 64 + g * 16) ^ sw)];
    }
#pragma unroll
    for (int kk = 0; kk < 4; kk++)
#pragma unroll
      for (int mi = 0; mi < MI; mi++)
#pragma unroll
        for (int nj = 0; nj < 2; nj++)
          acc[mi][nj] = __builtin_amdgcn_mfma_f32_16x16x32_bf16(a[cur][mi][kk], bfr[nj][kk], acc[mi][nj], 0, 0, 0);
    if (ibk + 1 < NBK)
      *(bf16x8*)&Bl[nxt][wofs] = cvt2(bu[(ibk + 1) & 1][0], bu[(ibk + 1) & 1][1]);
    __syncthreads();
  }

  long long co = (long long)blockIdx.y * 256 * ldc;
  int rr = (lane >> 4) << 2;
#pragma unroll
  for (int mi = 0; mi < MI; mi++)
#pragma unroll
    for (int nj = 0; nj < 2; nj++)
#pragma unroll
      for (int q = 0; q < 4; q++) {
        int row = m0 + w * (MI * 16) + mi * 16 + rr + q;
        long long idx = co + (long long)row * ldc + n0 + nj * 16 + r0;
        float vv = acc[mi][nj][q];
        if (CMODE == 0) ((float*)Cv)[idx] = vv;
        else            ((u16*)Cv)[idx] = f2bf(vv);
      }
}

// ---------------- gate_up GEMM + fused silu, M-split 2. grid (256, 2).
__global__ __launch_bounds__(512) void gemmGU(
    const u16* __restrict__ A, const float* __restrict__ B,
    u16* __restrict__ y)
{
  const int K = 1024, NBK = 8;
  __shared__ char Bl[2][8192];
  int n0 = blockIdx.x * 16;
  int m0 = blockIdx.y * 128;
  int tid = threadIdx.x, lane = tid & 63, w = tid >> 6;
  int r0 = lane & 15, g = lane >> 4;
  int trow = tid >> 4, tcol = tid & 15;

  const float* brow = (trow < 16)
      ? (B + (long long)(n0 + trow) * K)
      : (B + (long long)(4096 + n0 + trow - 16) * K);
  const float* bsrc = brow + tcol * 8;
  const u16* abase = A + (long long)(m0 + w * 16 + r0) * K + g * 8;
  int swr = (trow & 7) << 4;
  int wofs = trow * 256 + ((tcol * 16) ^ swr);

  {
    f32x4 u = *(const f32x4*)bsrc;
    f32x4 v = *(const f32x4*)(bsrc + 4);
    *(bf16x8*)&Bl[0][wofs] = cvt2(u, v);
  }
  f32x4 bu[2][2];
  bu[1][0] = *(const f32x4*)(bsrc + 128);
  bu[1][1] = *(const f32x4*)(bsrc + 132);

  bf16x8 a[2][4];
#pragma unroll
  for (int kk = 0; kk < 4; kk++)
    a[0][kk] = *(const bf16x8*)(abase + kk * 32);

  f32x4 acc[2];
  acc[0] = (f32x4){0.f, 0.f, 0.f, 0.f};
  acc[1] = (f32x4){0.f, 0.f, 0.f, 0.f};

  __syncthreads();

#pragma unroll
  for (int ibk = 0; ibk < NBK; ibk++) {
    const int cur = ibk & 1;
    const int nxt = cur ^ 1;
    if (ibk + 2 < NBK) {
      int ko2 = (ibk + 2) * 128;
      bu[ibk & 1][0] = *(const f32x4*)(bsrc + ko2);
      bu[ibk & 1][1] = *(const f32x4*)(bsrc + ko2 + 4);
    }
    if (ibk + 1 < NBK) {
      int ko = (ibk + 1) * 128;
#pragma unroll
      for (int kk = 0; kk < 4; kk++)
        a[nxt][kk] = *(const bf16x8*)(abase + ko + kk * 32);
    }
    bf16x8 bfr[2][4];
#pragma unroll
    for (int nj = 0; nj < 2; nj++) {
      int row = nj * 16 + r0;
      int rb = row * 256, sw = (row & 7) << 4;
#pragma unroll
      for (int kk = 0; kk < 4; kk++)
        bfr[nj][kk] = *(const bf16x8*)&Bl[cur][rb + ((kk * 64 + g * 16) ^ sw)];
    }
#pragma unroll
    for (int kk = 0; kk < 4; kk++)
#pragma unroll
      for (int nj = 0; nj < 2; nj++)
        acc[nj] = __builtin_amdgcn_mfma_f32_16x16x32_bf16(a[cur][kk], bfr[nj][kk], acc[nj], 0, 0, 0);
    if (ibk + 1 < NBK)
      *(bf16x8*)&Bl[nxt][wofs] = cvt2(bu[(ibk + 1) & 1][0], bu[(ibk + 1) & 1][1]);
    __syncthreads();
  }

  int rr = (lane >> 4) << 2;
#pragma unroll
  for (int q = 0; q < 4; q++) {
    int row = m0 + w * 16 + rr + q;
    float gv = acc[0][q], uv = acc[1][q];
    y[(long long)row * 4096 + n0 + r0] = f2bf((gv / (1.0f + __expf(-gv))) * uv);
  }
}

// ---------------- fused residual + rmsnorm (sum variant)
__global__ __launch_bounds__(256) void rms_fuse(const float* __restrict__ src,
                                                const float* __restrict__ parts, int np,
                                                float* __restrict__ hout, u16* __restrict__ x) {
  int s = blockIdx.x, tid = threadIdx.x;
  __shared__ float red[4];
  f32x4 hv = ((const f32x4*)(src + s * 1024))[tid];
  for (int p = 0; p < np; p++) {
    f32x4 pv = ((const f32x4*)(parts + (long long)p * 262144 + s * 1024))[tid];
    hv[0] += pv[0]; hv[1] += pv[1]; hv[2] += pv[2]; hv[3] += pv[3];
  }
  float ss = hv[0]*hv[0] + hv[1]*hv[1] + hv[2]*hv[2] + hv[3]*hv[3];
#pragma unroll
  for (int off = 32; off > 0; off >>= 1) ss += __shfl_xor(ss, off, 64);
  int lane = tid & 63, w = tid >> 6;
  if (lane == 0) red[w] = ss;
  __syncthreads();
  ss = red[0] + red[1] + red[2] + red[3];
  float r = 1.0f / sqrtf(ss);
  ((f32x4*)(hout + s * 1024))[tid] = hv;
  u16x4 o;
#pragma unroll
  for (int c = 0; c < 4; c++) o[c] = f2bf(hv[c] * r);
  ((u16x4*)x)[s * 256 + tid] = o;
}

// ---------------- final norm
__global__ __launch_bounds__(256) void final_fuse(const float* __restrict__ src,
                                                  const float* __restrict__ parts, int np,
                                                  const float* __restrict__ nw,
                                                  float* __restrict__ out) {
  int s = blockIdx.x, tid = threadIdx.x;
  __shared__ float red[4];
  f32x4 hv = ((const f32x4*)(src + s * 1024))[tid];
  for (int p = 0; p < np; p++) {
    f32x4 pv = ((const f32x4*)(parts + (long long)p * 262144 + s * 1024))[tid];
    hv[0] += pv[0]; hv[1] += pv[1]; hv[2] += pv[2]; hv[3] += pv[3];
  }
  float ss = hv[0]*hv[0] + hv[1]*hv[1] + hv[2]*hv[2] + hv[3]*hv[3];
#pragma unroll
  for (int off = 32; off > 0; off >>= 1) ss += __shfl_xor(ss, off, 64);
  int lane = tid & 63, w = tid >> 6;
  if (lane == 0) red[w] = ss;
  __syncthreads();
  ss = red[0] + red[1] + red[2] + red[3];
  float r = 1.0f / sqrtf(ss * (1.0f / 1024.0f) + 1e-6f);
  f32x4 wv = ((const f32x4*)nw)[tid];
  f32x4 o; o[0]=hv[0]*r*wv[0]; o[1]=hv[1]*r*wv[1]; o[2]=hv[2]*r*wv[2]; o[3]=hv[3]*r*wv[3];
  ((f32x4*)(out + s * 1024))[tid] = o;
}

// ---------------- transpose ALL layers' past K/V (once)
__global__ __launch_bounds__(256) void transpose_past(const float* __restrict__ pk,
                                                      const float* __restrict__ pv,
                                                      u16* __restrict__ Kb, u16* __restrict__ Vb) {
  __shared__ float tile[64][65];
  int t0 = blockIdx.x * 64;
  int kvh = blockIdx.y;
  int l = blockIdx.z >> 1, part = blockIdx.z & 1;
  int lk = l * 2 + kvh;
  int tid = threadIdx.x;
  if (part == 0) {
    const float* src = pk + (long long)lk * 64 * 2048;        // [d][t]
#pragma unroll
    for (int r = 0; r < 16; r++) {
      int idx = r * 256 + tid; int d = idx >> 6, t = idx & 63;
      tile[d][t] = src[d * 2048 + t0 + t];
    }
    __syncthreads();
    u16* dst = Kb + (long long)lk * 2304 * 64;                // [t][d]
#pragma unroll
    for (int r = 0; r < 16; r++) {
      int idx = r * 256 + tid; int t = idx >> 6, d = idx & 63;
      dst[(t0 + t) * 64 + d] = f2bf(tile[d][t]);
    }
  } else {
    const float* src = pv + (long long)lk * 2048 * 64;        // [t][d]
#pragma unroll
    for (int r = 0; r < 16; r++) {
      int idx = r * 256 + tid; int t = idx >> 6, d = idx & 63;
      tile[t][d] = src[(t0 + t) * 64 + d];
    }
    __syncthreads();
    u16* dst = Vb + (long long)lk * 64 * 2304;                // [d][t]
#pragma unroll
    for (int r = 0; r < 16; r++) {
      int idx = r * 256 + tid; int d = idx >> 6, t = idx & 63;
      dst[d * 2304 + t0 + t] = f2bf(tile[t][d]);
    }
  }
}

// ---------------- rope (sums 4 qkv partials) + scatter new q/k/v
__global__ __launch_bounds__(256) void rope_qkv(const float* __restrict__ P,
                                                const float* __restrict__ cs,
                                                const float* __restrict__ sn,
                                                u16* __restrict__ qb,
                                                u16* __restrict__ Kb,
                                                u16* __restrict__ Vb) {
  int s = blockIdx.x, tid = threadIdx.x;
  long long o0 = (long long)s * 1280;
  for (int i = tid; i < 1280; i += 256) {
    int hh = i >> 6, d = i & 63;
    float v = P[o0 + i] + P[327680 + o0 + i] + P[655360 + o0 + i] + P[983040 + o0 + i];
    if (hh < 18) {
      int j = (hh << 6) | ((d + 32) & 63);
      float vr = P[o0 + j] + P[327680 + o0 + j] + P[655360 + o0 + j] + P[983040 + o0 + j];
      v = v * cs[s * 64 + d] + vr * sn[s * 64 + d];
      if (hh < 16) qb[hh * 16384 + s * 64 + d] = f2bf(v);
      else         Kb[(hh - 16) * 147456 + (2048 + s) * 64 + d] = f2bf(v);
    } else {
      Vb[(hh - 18) * 147456 + d * 2304 + 2048 + s] = f2bf(v);
    }
  }
}

// ---------------- flash attention, 8-wave (verified round-14)
struct KV { bf16x8 kf[2][2]; bf16x8 vf[4]; };

__global__ __launch_bounds__(512) void flash_attn(
    const u16* __restrict__ qb, const u16* __restrict__ Kb2,
    const u16* __restrict__ Vb2, u16* __restrict__ oacc)
{
  __shared__ u16 Plds[8][16][36];
  __shared__ float Osh[8][16][68];
  __shared__ float msh[8][16];
  __shared__ float lsh[8][16];

  int hh = blockIdx.y, kvh = hh >> 3;
  int s0 = blockIdx.x * 16;
  int tid = threadIdx.x, lane = tid & 63, w = tid >> 6;
  int g = lane >> 4, r0 = lane & 15;

  const u16* Q  = qb  + hh * (256 * 64);
  const u16* Kh = Kb2 + kvh * (2304 * 64);
  const u16* Vh = Vb2 + kvh * (64 * 2304);

  bf16x8 qf[2];
#pragma unroll
  for (int kk = 0; kk < 2; kk++)
    qf[kk] = *(const bf16x8*)(Q + (s0 + r0) * 64 + kk * 32 + g * 8);

  f32x4 O[4];
#pragma unroll
  for (int dj = 0; dj < 4; dj++) O[dj] = (f32x4){0.f, 0.f, 0.f, 0.f};
  float m = -1e30f, l = 0.f;

  int t0s = w * 288;

  auto loadkv = [&](KV& d, int t0) {
#pragma unroll
    for (int tj = 0; tj < 2; tj++)
#pragma unroll
      for (int kk = 0; kk < 2; kk++)
        d.kf[tj][kk] = *(const bf16x8*)(Kh + (t0 + tj * 16 + r0) * 64 + kk * 32 + g * 8);
#pragma unroll
    for (int dj = 0; dj < 4; dj++)
      d.vf[dj] = *(const bf16x8*)(Vh + (dj * 16 + r0) * 2304 + t0 + g * 8);
  };

  auto step = [&](KV& kv, int t0) {
    f32x4 sc[2];
#pragma unroll
    for (int tj = 0; tj < 2; tj++) {
      f32x4 z = (f32x4){0.f, 0.f, 0.f, 0.f};
      z = __builtin_amdgcn_mfma_f32_16x16x32_bf16(kv.kf[tj][0], qf[0], z, 0, 0, 0);
      z = __builtin_amdgcn_mfma_f32_16x16x32_bf16(kv.kf[tj][1], qf[1], z, 0, 0, 0);
      sc[tj] = z;
    }
    if (t0 + 31 > 2048 + s0) {
#pragma unroll
      for (int tj = 0; tj < 2; tj++)
#pragma unroll
        for (int q = 0; q < 4; q++) {
          int tg = t0 + tj * 16 + g * 4 + q;
          int sg = s0 + r0;
          if (tg > 2048 + sg) sc[tj][q] = -1e30f;
        }
    }
    float rm = -1e30f;
#pragma unroll
    for (int tj = 0; tj < 2; tj++)
#pragma unroll
      for (int q = 0; q < 4; q++) rm = fmaxf(rm, sc[tj][q]);
    rm = fmaxf(rm, __shfl_xor(rm, 16, 64));
    rm = fmaxf(rm, __shfl_xor(rm, 32, 64));
    float mn = fmaxf(m, rm);
    float sca = __expf(m - mn);
    float rs = 0.f;
#pragma unroll
    for (int tj = 0; tj < 2; tj++)
#pragma unroll
      for (int q = 0; q < 4; q++) {
        sc[tj][q] = __expf(sc[tj][q] - mn);
        rs += sc[tj][q];
      }
    rs += __shfl_xor(rs, 16, 64);
    rs += __shfl_xor(rs, 32, 64);
    l = l * sca + rs;
    m = mn;
#pragma unroll
    for (int dj = 0; dj < 4; dj++) {
      O[dj][0] *= sca; O[dj][1] *= sca; O[dj][2] *= sca; O[dj][3] *= sca;
    }
#pragma unroll
    for (int tj = 0; tj < 2; tj++) {
      u16x4 pw;
#pragma unroll
      for (int q = 0; q < 4; q++) pw[q] = f2bf(sc[tj][q]);
      *(u16x4*)&Plds[w][r0][tj * 16 + g * 4] = pw;
    }
    u16x4 plo = *(const u16x4*)&Plds[w][r0][g * 8];
    u16x4 phi = *(const u16x4*)&Plds[w][r0][g * 8 + 4];
    union { bf16x8 v; u16x4 h[2]; } pu;
    pu.h[0] = plo; pu.h[1] = phi;
#pragma unroll
    for (int dj = 0; dj < 4; dj++)
      O[dj] = __builtin_amdgcn_mfma_f32_16x16x32_bf16(kv.vf[dj], pu.v, O[dj], 0, 0, 0);
  };

  KV ba, bb;
  loadkv(ba, t0s);
#pragma unroll 1
  for (int p = 0; p < 4; p++) {
    int t0 = t0s + p * 64;
    loadkv(bb, t0 + 32);
    step(ba, t0);
    loadkv(ba, t0 + 64);
    step(bb, t0 + 32);
  }
  step(ba, t0s + 256);

#pragma unroll
  for (int dj = 0; dj < 4; dj++)
    *(f32x4*)&Osh[w][r0][dj * 16 + g * 4] = O[dj];
  if (g == 0) { msh[w][r0] = m; lsh[w][r0] = l; }
  __syncthreads();

  if (tid < 256) {
    int row = tid >> 4, c0 = (tid & 15) * 4;
    float M = -1e30f;
#pragma unroll
    for (int w8 = 0; w8 < 8; w8++) M = fmaxf(M, msh[w8][row]);
    float L = 0.f;
    float a0 = 0.f, a1 = 0.f, a2 = 0.f, a3 = 0.f;
#pragma unroll
    for (int w8 = 0; w8 < 8; w8++) {
      float e = __expf(msh[w8][row] - M);
      L += lsh[w8][row] * e;
      f32x4 ov = *(const f32x4*)&Osh[w8][row][c0];
      a0 += e * ov[0]; a1 += e * ov[1]; a2 += e * ov[2]; a3 += e * ov[3];
    }
    float inv = 1.0f / L;
    u16x4 o4;
    o4[0] = f2bf(a0 * inv); o4[1] = f2bf(a1 * inv);
    o4[2] = f2bf(a2 * inv); o4[3] = f2bf(a3 * inv);
    *(u16x4*)(oacc + (long long)(s0 + row) * 1024 + hh * 64 + c0) = o4;
  }
}

// ---------------- launch ----------------
extern "C" void kernel_launch(void* const* d_in, const int* in_sizes, int n_in,
                              void* d_out, int out_size, void* d_ws, size_t ws_size,
                              hipStream_t stream) {
  (void)in_sizes; (void)n_in; (void)out_size; (void)ws_size;
  const float* hs   = (const float*)d_in[0];
  const float* rc   = (const float*)d_in[1];
  const float* rs   = (const float*)d_in[2];
  const float* pk   = (const float*)d_in[4];
  const float* pv   = (const float*)d_in[5];
  const float* qkvw = (const float*)d_in[6];
  const float* ow   = (const float*)d_in[7];
  const float* guw  = (const float*)d_in[8];
  const float* dw   = (const float*)d_in[9];
  const float* nw   = (const float*)d_in[10];
  float* out = (float*)d_out;

  char* base = (char*)d_ws;
  float* h   = (float*)(base + 0);            // 1 MB
  u16*  x    = (u16*)(base + 1048576);        // 0.5 MB
  float* Pq  = (float*)(base + 1572864);      // 5 MB    [4][256][1280]
  float* Po  = (float*)(base + 6815744);      // 4 MB    [4][256][1024]
  float* Pd  = (float*)(base + 11010048);     // 4 MB    [4][256][1024]
  u16*  y    = (u16*)(base + 15204352);       // 2 MB    [256][4096] bf16
  u16*  oacc = (u16*)(base + 17301504);       // 0.5 MB
  u16*  qb   = (u16*)(base + 17825792);       // 0.5 MB
  u16*  Kb   = (u16*)(base + 18350080);       // 4.5 MB  [8][2][2304][64]
  u16*  Vb   = (u16*)(base + 23068672);       // 4.5 MB  [8][2][64][2304]

  transpose_past<<<dim3(32, 2, 16), 256, 0, stream>>>(pk, pv, Kb, Vb);

  for (int l = 0; l < 8; ++l) {
    u16* Kbl = Kb + (long long)l * 2 * 2304 * 64;
    u16* Vbl = Vb + (long long)l * 2 * 64 * 2304;

    if (l == 0)
      rms_fuse<<<256, 256, 0, stream>>>(hs, nullptr, 0, h, x);
    else
      rms_fuse<<<256, 256, 0, stream>>>(h, Pd, 4, h, x);

    // qkv: 40 n-tiles x 4 ksplit x 2 msplit = 320 blocks, NBK=2
    gemmW<0, 2, 1><<<dim3(40, 4, 2), 512, 0, stream>>>(
        x, qkvw + (long long)l * 1310720, Pq, 1024, 1280);
    rope_qkv<<<256, 256, 0, stream>>>(Pq, rc, rs, qb, Kbl, Vbl);
    flash_attn<<<dim3(16, 16), 512, 0, stream>>>(qb, Kbl, Vbl, oacc);
    // o-proj: 32 x 4 ksplit x 2 msplit = 256 blocks, NBK=2
    gemmW<0, 2, 1><<<dim3(32, 4, 2), 512, 0, stream>>>(
        oacc, ow + (long long)l * 1048576, Po, 1024, 1024);
    rms_fuse<<<256, 256, 0, stream>>>(h, Po, 4, h, x);
    // gate_up: 256 n-tiles x 2 msplit = 512 blocks, NBK=8
    gemmGU<<<dim3(256, 2), 512, 0, stream>>>(
        x, guw + (long long)l * 8388608, y);
    // down: 32 x 4 ksplit x 2 msplit = 256 blocks, NBK=8
    gemmW<0, 8, 1><<<dim3(32, 4, 2), 512, 0, stream>>>(
        y, dw + (long long)l * 4194304, Pd, 4096, 1024);
  }
  final_fuse<<<256, 256, 0, stream>>>(h, Pd, 4, nw, out);
}